// Round 14
// baseline (257.204 us; speedup 1.0000x reference)
//
#include <hip/hip_runtime.h>

#define B_DIM 2048
#define IN_DIM 1024
#define OUT_DIM 1024
#define K_KNOTS 20
#define KR (IN_DIM * K_KNOTS)   // 20480 reduction dim
#define OUT_ELEMS (B_DIM * OUT_DIM)
#define KS 8                    // K-split (one slice per XCD)

// ---- prep sizing ----
#define NPAIRS (B_DIM * IN_DIM * 5 / 2)           // 5,242,880 basis-pair threads
#define NB_BASIS_BLK (NPAIRS / 256)               // 20480 blocks
#define NW4 (OUT_DIM * KR / 8)                    // 2,621,440 uint4 outputs
#define NB_W_BLK (NW4 / 256)                      // 10240 blocks

typedef __bf16 bf16x8 __attribute__((ext_vector_type(8)));
typedef float  f32x4  __attribute__((ext_vector_type(4)));

#define MFMA16(a, b, c) __builtin_amdgcn_mfma_f32_16x16x32_bf16(a, b, c, 0, 0, 0)

__device__ __forceinline__ unsigned short f2bf(float f) {
    unsigned int u = __float_as_uint(f);
    unsigned int r = u + 0x7fffu + ((u >> 16) & 1u);   // RNE; no NaN inputs here
    return (unsigned short)(r >> 16);
}

__device__ __forceinline__ unsigned int pack2(float lo, float hi) {
    return (unsigned int)f2bf(lo) | ((unsigned int)f2bf(hi) << 16);
}

__device__ __forceinline__ void async_load16(const void* g, void* l) {
    __builtin_amdgcn_global_load_lds(
        (const __attribute__((address_space(1))) void*)g,
        (__attribute__((address_space(3))) void*)l,
        16, 0, 0);
}

// ============================================================================
// prep: basis bf16 (paired-quad threads, 16B stores) + W fp32->bf16.
// LEDGER (do not revisit): A-exp fused in gemm = 187us (R6); B-f32 fused in
// gemm = 146us (R7); atomic K-split epilogue = +31us (R5); cooperative
// 1-block/CU fusion = prep at 550 GB/s (R4).
// ============================================================================
__global__ void __launch_bounds__(256) prep_kernel(
        const float* __restrict__ x,
        const float4* __restrict__ Wsrc,
        const float* __restrict__ knots,
        uint4* __restrict__ basis_out,
        uint4* __restrict__ w_out) {
    if (blockIdx.x < NB_BASIS_BLK) {
        const unsigned int p  = blockIdx.x * 256 + threadIdx.x;   // pair index
        const unsigned int n0 = 2 * p;                            // first quad
        const unsigned int q0  = n0 % 5u;
        const unsigned int bi0 = n0 / 5u;
        const float t0   = knots[0];
        const float h    = knots[1] - t0;
        const float invh = 1.0f / h;

        const bool cross = (q0 == 4u);
        const unsigned int bi1 = bi0 + (cross ? 1u : 0u);
        const float xv0 = x[bi0];
        const float xv1 = x[bi1];              // == xv0 when !cross (cached)
        const float kA = (float)(4u * q0);
        const float kB = cross ? 0.f : kA + 4.f;

        float v[8];
#pragma unroll
        for (int j = 0; j < 4; ++j) {
            float t = __builtin_fmaf(kA + (float)j, h, t0);
            float d = (xv0 - t) * invh;
            v[j] = __expf(-0.5f * d * d);
        }
#pragma unroll
        for (int j = 0; j < 4; ++j) {
            float t = __builtin_fmaf(kB + (float)j, h, t0);
            float d = (xv1 - t) * invh;
            v[4 + j] = __expf(-0.5f * d * d);
        }
        uint4 o;
        o.x = pack2(v[0], v[1]); o.y = pack2(v[2], v[3]);
        o.z = pack2(v[4], v[5]); o.w = pack2(v[6], v[7]);
        basis_out[p] = o;
    } else {
        unsigned int t = (blockIdx.x - NB_BASIS_BLK) * 256 + threadIdx.x;
        float4 a = Wsrc[2 * t];
        float4 b = Wsrc[2 * t + 1];
        uint4 o;
        o.x = pack2(a.x, a.y);
        o.y = pack2(a.z, a.w);
        o.z = pack2(b.x, b.y);
        o.w = pack2(b.z, b.w);
        w_out[t] = o;
    }
}

// ============================================================================
// 256x256 / BK=64 / 8-wave GEMM, R14 = R12's one-phase-deep ds_read pipeline
// (functionally verified in R12: passed, absmax 0.125) with the REGISTER
// BUDGET FIXED: __launch_bounds__(512) not (512,2).
//
// R12 failure diagnosis: the ",2" min-waves/EU bound capped the allocator at
// 128 VGPRs; the pipeline head (a0/b0 live across tile_steps) spilled to
// scratch (VGPR_Count=128 exactly, WRITE_SIZE +12MB) -> 108us. HW truth: the
// 128KiB LDS already forces 1 block/CU = 8 waves = 2/SIMD, which fits at up
// to 256 VGPR/wave (m69). A 512-thread block implies the 256 cap
// automatically -- the ",2" was over-conservative by 2x.
//
// Schedule (= R12; R11's vmcnt chain + read-issue rotated one phase early):
//   ph4(t-1): issue a0,b0 (k0)        -> awaited ph1 lgkm(8)
//   ph1: stage A(t+1).k0; VMCNT(2|0); BARRIER; issue a1,b1 (k1); lgkm(8);
//        MFMA i0-3 @ k0   (ds reads drain UNDER the MFMA cluster)
//   ph2: stage B(t+1).k0; BARRIER; issue s0; lgkm(4); MFMA i0-3 @ k1
//   ph3: stage A(t+1).k1; BARRIER; issue s1; lgkm(4); MFMA i4-7 @ k0
//   ph4: stage B(t+1).k1; VMCNT(4); BARRIER; issue next a0,b0; lgkm(8);
//        MFMA i4-7 @ k1
// vmcnt BEFORE barrier = cross-wave publish (R10 lesson). Swizzle key
// k(R)=(R>>1)&3 (0 conflicts measured, R11/R13).
// COMPLETE LEDGER: R1=90 R2=97 R3/R8=84 R9=81.5(racy) R10=TRIPWIRE
// R11/R13=80.5/78.7 (known-good fallback) R12=108.5 (spill) R14=this.
// Decision rule: VGPR>=256 w/ scratch OR gemm >=79 -> revert to R13, stop.
// ============================================================================
#define AOF(s, kh) (((s) * 2 + (kh)) * 8192)
#define BOF(s, kh) (32768 + ((s) * 2 + (kh)) * 8192)

template <int S>
__device__ __forceinline__ void tile_step(
        int t, int ntiles,
        const unsigned short* __restrict__ Ab,
        const unsigned short* __restrict__ Bb,
        unsigned short* lds,
        f32x4 (&acc)[8][4],
        bf16x8 (&a0)[4], bf16x8 (&b0)[4],   // pipeline head: tile t k0 frags (in flight)
        int m0, int n0, int k0,
        int wave, int rowA, int rowB,
        int srow32, int scol32) {
    const int kb1 = k0 + (t + 1) * 64;
    const bool st = (t + 1 < ntiles);

    auto stage_half = [&](const unsigned short* __restrict__ src, int grow,
                          int kc, int lbase) {
        const unsigned short* g =
            src + (size_t)(grow + wave * 32 + srow32) * KR + kc + scol32;
        async_load16(g,                   &lds[lbase + wave * 1024]);
        async_load16(g + (size_t)16 * KR, &lds[lbase + wave * 1024 + 512]);
    };

    bf16x8 a1[4], b1[4], s0[4], s1[4];

    // ---- ph1: stage A(t+1).k0; VMCNT(2|0); BARRIER; issue k1 reads;
    //          lgkm(8) [a0,b0 done]; MFMA i0..3 @ k0 ----
    if (st) {
        stage_half(Ab, m0, kb1, AOF(S ^ 1, 0));
        asm volatile("s_waitcnt vmcnt(2)" ::: "memory");   // confirms t.k1
    } else {
        asm volatile("s_waitcnt vmcnt(0)" ::: "memory");
    }
    __builtin_amdgcn_s_barrier();
    asm volatile("" ::: "memory");
#pragma unroll
    for (int i = 0; i < 4; ++i) a1[i] = *(const bf16x8*)&lds[AOF(S, 1) + rowA + i * 512];
#pragma unroll
    for (int j = 0; j < 4; ++j) b1[j] = *(const bf16x8*)&lds[BOF(S, 1) + rowB + j * 512];
    __builtin_amdgcn_sched_barrier(0);
    asm volatile("s_waitcnt lgkmcnt(8)" ::: "memory");     // a0,b0 complete
    __builtin_amdgcn_sched_barrier(0);
    __builtin_amdgcn_s_setprio(1);
#pragma unroll
    for (int i = 0; i < 4; ++i)
#pragma unroll
        for (int j = 0; j < 4; ++j)
            acc[i][j] = MFMA16(a0[i], b0[j], acc[i][j]);
    __builtin_amdgcn_s_setprio(0);

    // ---- ph2: stage B(t+1).k0; BARRIER; issue s0 reads;
    //          lgkm(4) [a1,b1 done]; MFMA i0..3 @ k1 ----
    if (st) stage_half(Bb, n0, kb1, BOF(S ^ 1, 0));
    __builtin_amdgcn_s_barrier();
    asm volatile("" ::: "memory");
#pragma unroll
    for (int i = 0; i < 4; ++i) s0[i] = *(const bf16x8*)&lds[AOF(S, 0) + rowA + (4 + i) * 512];
    __builtin_amdgcn_sched_barrier(0);
    asm volatile("s_waitcnt lgkmcnt(4)" ::: "memory");     // a1,b1 complete
    __builtin_amdgcn_sched_barrier(0);
    __builtin_amdgcn_s_setprio(1);
#pragma unroll
    for (int i = 0; i < 4; ++i)
#pragma unroll
        for (int j = 0; j < 4; ++j)
            acc[i][j] = MFMA16(a1[i], b1[j], acc[i][j]);
    __builtin_amdgcn_s_setprio(0);

    // ---- ph3: stage A(t+1).k1; BARRIER; issue s1 reads;
    //          lgkm(4) [s0 done]; MFMA i4..7 @ k0 ----
    if (st) stage_half(Ab, m0, kb1 + 32, AOF(S ^ 1, 1));
    __builtin_amdgcn_s_barrier();
    asm volatile("" ::: "memory");
#pragma unroll
    for (int i = 0; i < 4; ++i) s1[i] = *(const bf16x8*)&lds[AOF(S, 1) + rowA + (4 + i) * 512];
    __builtin_amdgcn_sched_barrier(0);
    asm volatile("s_waitcnt lgkmcnt(4)" ::: "memory");     // s0 complete
    __builtin_amdgcn_sched_barrier(0);
    __builtin_amdgcn_s_setprio(1);
#pragma unroll
    for (int i = 0; i < 4; ++i)
#pragma unroll
        for (int j = 0; j < 4; ++j)
            acc[4 + i][j] = MFMA16(s0[i], b0[j], acc[4 + i][j]);
    __builtin_amdgcn_s_setprio(0);

    // ---- ph4: stage B(t+1).k1; VMCNT(4); BARRIER; issue next-tile k0 reads
    //          into a0,b0; lgkm(8) [s1 done]; MFMA i4..7 @ k1 ----
    if (st) {
        stage_half(Bb, n0, kb1 + 32, BOF(S ^ 1, 1));
        asm volatile("s_waitcnt vmcnt(4)" ::: "memory");   // confirms (t+1).k0
    }
    __builtin_amdgcn_s_barrier();
    asm volatile("" ::: "memory");
    if (st) {
#pragma unroll
        for (int i = 0; i < 4; ++i) a0[i] = *(const bf16x8*)&lds[AOF(S ^ 1, 0) + rowA + i * 512];
#pragma unroll
        for (int j = 0; j < 4; ++j) b0[j] = *(const bf16x8*)&lds[BOF(S ^ 1, 0) + rowB + j * 512];
        __builtin_amdgcn_sched_barrier(0);
        asm volatile("s_waitcnt lgkmcnt(8)" ::: "memory"); // s1 complete
    } else {
        asm volatile("s_waitcnt lgkmcnt(0)" ::: "memory");
    }
    __builtin_amdgcn_sched_barrier(0);
    __builtin_amdgcn_s_setprio(1);
#pragma unroll
    for (int i = 0; i < 4; ++i)
#pragma unroll
        for (int j = 0; j < 4; ++j)
            acc[4 + i][j] = MFMA16(s1[i], b1[j], acc[4 + i][j]);
    __builtin_amdgcn_s_setprio(0);
}

__global__ void __launch_bounds__(512)   // NOT (512,2): 8-wave block implies
kan_gemm8(const unsigned short* __restrict__ Ab,  // the 256-VGPR cap; ",2"
          const unsigned short* __restrict__ Bb,  // forced 128 and spilled (R12)
          float* __restrict__ part) {             // (KS, 2048, 1024) partials
    __shared__ __align__(16) unsigned short lds[65536];   // 128 KiB

    constexpr int KPBk   = KR / KS;          // 2560
    constexpr int NTILES = KPBk / 64;        // 40

    const int id  = blockIdx.x;
    const int z   = id & 7;                  // K-split slice -> one per XCD
    const int ord = id >> 3;                 // 0..31
    const int mt  = ord & 7;
    const int nt  = ord >> 3;                // 0..3
    const int m0  = mt * 256;
    const int n0  = nt * 256;
    const int k0  = z * KPBk;

    const int tid  = threadIdx.x;
    const int wave = tid >> 6;               // 0..7
    const int lane = tid & 63;
    const int wm   = wave >> 2;              // 0..1 -> wave owns 128 M-rows
    const int wn   = wave & 3;               // 0..3 -> wave owns 64 N-cols

    const int srow32 = lane >> 2;                            // staging row 0..15
    const int scol32 = ((lane & 3) ^ ((lane >> 3) & 3)) * 8; // key=(R>>1)&3

    auto stage_half = [&](const unsigned short* __restrict__ src, int grow,
                          int kc, int lbase) {
        const unsigned short* g =
            src + (size_t)(grow + wave * 32 + srow32) * KR + kc + scol32;
        async_load16(g,                   &lds[lbase + wave * 1024]);
        async_load16(g + (size_t)16 * KR, &lds[lbase + wave * 1024 + 512]);
    };

    f32x4 acc[8][4];
#pragma unroll
    for (int i = 0; i < 8; ++i)
#pragma unroll
        for (int j = 0; j < 4; ++j) acc[i][j] = (f32x4){0.f, 0.f, 0.f, 0.f};

    const int q    = lane >> 4;
    const int r15  = lane & 15;
    const int cs   = (q ^ ((r15 >> 1) & 3)) * 8;   // read slot, key=(R>>1)&3
    const int rowA = (wm * 128 + r15) * 32 + cs;
    const int rowB = (wn * 64 + r15) * 32 + cs;

    // prologue: stage tile 0; vmcnt(4) confirms k0; prime pipeline head
    stage_half(Ab, m0, k0,      AOF(0, 0));
    stage_half(Bb, n0, k0,      BOF(0, 0));
    stage_half(Ab, m0, k0 + 32, AOF(0, 1));
    stage_half(Bb, n0, k0 + 32, BOF(0, 1));
    asm volatile("s_waitcnt vmcnt(4)" ::: "memory");
    __builtin_amdgcn_s_barrier();
    asm volatile("" ::: "memory");
    bf16x8 a0[4], b0[4];
#pragma unroll
    for (int i = 0; i < 4; ++i) a0[i] = *(const bf16x8*)&lds[AOF(0, 0) + rowA + i * 512];
#pragma unroll
    for (int j = 0; j < 4; ++j) b0[j] = *(const bf16x8*)&lds[BOF(0, 0) + rowB + j * 512];
    __builtin_amdgcn_sched_barrier(0);

    for (int tt = 0; tt < NTILES; tt += 2) {
        tile_step<0>(tt,     NTILES, Ab, Bb, lds, acc, a0, b0, m0, n0, k0,
                     wave, rowA, rowB, srow32, scol32);
        tile_step<1>(tt + 1, NTILES, Ab, Bb, lds, acc, a0, b0, m0, n0, k0,
                     wave, rowA, rowB, srow32, scol32);
    }

    // epilogue: partials; C/D layout col=lane&15, row=(lane>>4)*4+reg
    float* dst = part + (size_t)z * OUT_ELEMS;
#pragma unroll
    for (int i = 0; i < 8; ++i)
#pragma unroll
        for (int j = 0; j < 4; ++j)
#pragma unroll
            for (int r = 0; r < 4; ++r) {
                const int row = m0 + wm * 128 + i * 16 + q * 4 + r;
                const int c   = n0 + wn * 64  + j * 16 + r15;
                dst[(size_t)row * OUT_DIM + c] = acc[i][j][r];
            }
}

// ---------------- reduce KS partial slices -> out ----------------------------
template <int KSr>
__global__ void kan_reduce(const float* __restrict__ part, float* __restrict__ out) {
    const int idx = (blockIdx.x * 256 + threadIdx.x) * 4;
    f32x4 s = *(const f32x4*)(part + idx);
#pragma unroll
    for (int z = 1; z < KSr; ++z)
        s += *(const f32x4*)(part + (size_t)z * OUT_ELEMS + idx);
    *(f32x4*)(out + idx) = s;
}

// ---------------- fallback (ws too small): correctness-only fp32 -------------
__global__ void kan_fallback(const float* __restrict__ x,
                             const float* __restrict__ W,
                             const float* __restrict__ knots,
                             float* __restrict__ out) {
    __shared__ float basis[256 * K_KNOTS];
    const int b = blockIdx.x;
    const int o = blockIdx.y * blockDim.x + threadIdx.x;
    const float invh = 1.0f / (knots[1] - knots[0]);
    const float* w = W + (size_t)o * KR;
    float sum = 0.f;
    for (int i0 = 0; i0 < IN_DIM; i0 += 256) {
        __syncthreads();
        for (int idx = threadIdx.x; idx < 256 * K_KNOTS; idx += blockDim.x) {
            const int i = i0 + idx / K_KNOTS;
            const int k = idx % K_KNOTS;
            const float d = (x[(size_t)b * IN_DIM + i] - knots[k]) * invh;
            basis[idx] = __expf(-0.5f * d * d);
        }
        __syncthreads();
        for (int r = 0; r < 256 * K_KNOTS; ++r)
            sum += basis[r] * w[(size_t)i0 * K_KNOTS + r];
    }
    out[(size_t)b * OUT_DIM + o] = sum;
}

extern "C" void kernel_launch(void* const* d_in, const int* in_sizes, int n_in,
                              void* d_out, int out_size, void* d_ws, size_t ws_size,
                              hipStream_t stream) {
    const float* x     = (const float*)d_in[0];
    const float* W     = (const float*)d_in[1];
    const float* knots = (const float*)d_in[2];
    float* out = (float*)d_out;

    const size_t basis_bytes = (size_t)B_DIM * KR * 2;              // 80 MiB
    const size_t wb_bytes    = (size_t)OUT_DIM * KR * 2;            // 40 MiB
    const size_t part_bytes  = (size_t)KS * OUT_ELEMS * 4;          // 64 MiB

    unsigned short* Ab = (unsigned short*)d_ws;
    unsigned short* Bb = (unsigned short*)((char*)d_ws + basis_bytes);
    float* part = (float*)((char*)d_ws + basis_bytes + wb_bytes);

    if (ws_size >= basis_bytes + wb_bytes + part_bytes) {
        // main path: vectorized prep + pipelined gemm (256-VGPR budget) + reduce.
        prep_kernel<<<dim3(NB_BASIS_BLK + NB_W_BLK), dim3(256), 0, stream>>>(
            x, (const float4*)W, knots, (uint4*)Ab, (uint4*)Bb);
        kan_gemm8<<<dim3(256), dim3(512), 0, stream>>>(Ab, Bb, part);
        kan_reduce<KS><<<dim3(OUT_ELEMS / (256 * 4)), dim3(256), 0, stream>>>(part, out);
    } else {
        kan_fallback<<<dim3(B_DIM, OUT_DIM / 256), dim3(256), 0, stream>>>(x, W, knots, out);
    }
}

// Round 15
// 243.589 us; speedup vs baseline: 1.0559x; 1.0559x over previous
//
#include <hip/hip_runtime.h>

#define B_DIM 2048
#define IN_DIM 1024
#define OUT_DIM 1024
#define K_KNOTS 20
#define KR (IN_DIM * K_KNOTS)   // 20480 reduction dim
#define OUT_ELEMS (B_DIM * OUT_DIM)
#define KS 8                    // K-split (one slice per XCD)

// ---- prep sizing ----
#define NPAIRS (B_DIM * IN_DIM * 5 / 2)           // 5,242,880 basis-pair threads
#define NB_BASIS_BLK (NPAIRS / 256)               // 20480 blocks
#define NW4 (OUT_DIM * KR / 8)                    // 2,621,440 uint4 outputs
#define NB_W_BLK (NW4 / 256)                      // 10240 blocks

typedef __bf16 bf16x8 __attribute__((ext_vector_type(8)));
typedef float  f32x4  __attribute__((ext_vector_type(4)));

#define MFMA16(a, b, c) __builtin_amdgcn_mfma_f32_16x16x32_bf16(a, b, c, 0, 0, 0)

__device__ __forceinline__ unsigned short f2bf(float f) {
    unsigned int u = __float_as_uint(f);
    unsigned int r = u + 0x7fffu + ((u >> 16) & 1u);   // RNE; no NaN inputs here
    return (unsigned short)(r >> 16);
}

__device__ __forceinline__ unsigned int pack2(float lo, float hi) {
    return (unsigned int)f2bf(lo) | ((unsigned int)f2bf(hi) << 16);
}

__device__ __forceinline__ void async_load16(const void* g, void* l) {
    __builtin_amdgcn_global_load_lds(
        (const __attribute__((address_space(1))) void*)g,
        (__attribute__((address_space(3))) void*)l,
        16, 0, 0);
}

// ============================================================================
// prep: basis bf16 (paired-quad threads, 16B stores) + W fp32->bf16.
// LEDGER (do not revisit): A-exp fused in gemm = 187us (R6); B-f32 fused in
// gemm = 146us (R7); atomic K-split epilogue = +31us (R5); cooperative
// 1-block/CU fusion = prep at 550 GB/s (R4).
// ============================================================================
__global__ void __launch_bounds__(256) prep_kernel(
        const float* __restrict__ x,
        const float4* __restrict__ Wsrc,
        const float* __restrict__ knots,
        uint4* __restrict__ basis_out,
        uint4* __restrict__ w_out) {
    if (blockIdx.x < NB_BASIS_BLK) {
        const unsigned int p  = blockIdx.x * 256 + threadIdx.x;   // pair index
        const unsigned int n0 = 2 * p;                            // first quad
        const unsigned int q0  = n0 % 5u;
        const unsigned int bi0 = n0 / 5u;
        const float t0   = knots[0];
        const float h    = knots[1] - t0;
        const float invh = 1.0f / h;

        const bool cross = (q0 == 4u);
        const unsigned int bi1 = bi0 + (cross ? 1u : 0u);
        const float xv0 = x[bi0];
        const float xv1 = x[bi1];              // == xv0 when !cross (cached)
        const float kA = (float)(4u * q0);
        const float kB = cross ? 0.f : kA + 4.f;

        float v[8];
#pragma unroll
        for (int j = 0; j < 4; ++j) {
            float t = __builtin_fmaf(kA + (float)j, h, t0);
            float d = (xv0 - t) * invh;
            v[j] = __expf(-0.5f * d * d);
        }
#pragma unroll
        for (int j = 0; j < 4; ++j) {
            float t = __builtin_fmaf(kB + (float)j, h, t0);
            float d = (xv1 - t) * invh;
            v[4 + j] = __expf(-0.5f * d * d);
        }
        uint4 o;
        o.x = pack2(v[0], v[1]); o.y = pack2(v[2], v[3]);
        o.z = pack2(v[4], v[5]); o.w = pack2(v[6], v[7]);
        basis_out[p] = o;
    } else {
        unsigned int t = (blockIdx.x - NB_BASIS_BLK) * 256 + threadIdx.x;
        float4 a = Wsrc[2 * t];
        float4 b = Wsrc[2 * t + 1];
        uint4 o;
        o.x = pack2(a.x, a.y);
        o.y = pack2(a.z, a.w);
        o.z = pack2(b.x, b.y);
        o.w = pack2(b.z, b.w);
        w_out[t] = o;
    }
}

// ============================================================================
// 256x256 / BK=64 / 8-wave GEMM = R11/R13 VERBATIM -- FINAL (measured best:
// 78.7-80.5us, MfmaUtil 46-48%, 0 bank conflicts, race-free, VGPR 124).
//
// COMPLETE SCHEDULE LEDGER (15 rounds -- do not restructure):
//   R1 unbalanced phases      90us   R2 top-loaded reads      97us
//   R3/R8 balanced lockstep   84us   R9 vmcnt+bad swizzle     81.5 (racy)
//   R10 vmcnt-after-barrier   TRIPWIRE (cross-wave race)
//   R11/R13 vmcnt-BEFORE-barrier 78.7-80.5us <- FINAL
//   R12 ds_read pipeline @(512,2) 108.5 (spill at forced 128-VGPR cap)
//   R14 ds_read pipeline @(512)   103   (allocator still picks 128, spills:
//        occupancy heuristic + sched_barrier pins; refuted at every budget)
//
// Schedule (slot S = t&1; regions = 256 rows x 32 k-cols, 16 KB):
//   ph1: read k0 [8 ds]; stage A(t+1).k0; VMCNT(2|0) -> BARRIER -> MFMA i0-3 @ k0
//        (vmcnt confirms A(t).k1+B(t).k1, staged in t-1 ph3/ph4; vmcnt is
//        per-wave so it must PRECEDE the barrier: wave confirms its slice,
//        barrier publishes block-wide)
//   ph2: read k1 [8 ds]; stage B(t+1).k0            -> BARRIER -> MFMA i0-3 @ k1
//   ph3: read k0 i4-7 [4]; stage A(t+1).k1          -> BARRIER -> MFMA i4-7 @ k0
//   ph4: read k1 i4-7 [4]; stage B(t+1).k1; VMCNT(4)-> BARRIER -> MFMA i4-7 @ k1
// Steady state never drains vmcnt to 0. Swizzle involution key k(R)=(R>>1)&3:
//   write: src col = ((l&3) ^ ((l>>3)&3))*8; read: phys slot = q ^ ((r15>>1)&3)
// (covers all 8 slots x2 lanes per 16-lane quarter = 2-way = free, m136).
// ============================================================================
#define AOF(s, kh) (((s) * 2 + (kh)) * 8192)
#define BOF(s, kh) (32768 + ((s) * 2 + (kh)) * 8192)

template <int S>
__device__ __forceinline__ void tile_step(
        int t, int ntiles,
        const unsigned short* __restrict__ Ab,
        const unsigned short* __restrict__ Bb,
        unsigned short* lds,
        f32x4 (&acc)[8][4],
        int m0, int n0, int k0,
        int wave, int rowA, int rowB,
        int srow32, int scol32) {
    const int kb1 = k0 + (t + 1) * 64;
    const bool st = (t + 1 < ntiles);

    auto stage_half = [&](const unsigned short* __restrict__ src, int grow,
                          int kc, int lbase) {
        const unsigned short* g =
            src + (size_t)(grow + wave * 32 + srow32) * KR + kc + scol32;
        async_load16(g,                   &lds[lbase + wave * 1024]);
        async_load16(g + (size_t)16 * KR, &lds[lbase + wave * 1024 + 512]);
    };

    bf16x8 a0[4], a1[4], b0[4], b1[4], s0[4], s1[4];

    // ---- phase 1: reads k0 + stage A(t+1).k0 + VMCNT(2|0) -> MFMA i0..3 @ k0 ----
#pragma unroll
    for (int i = 0; i < 4; ++i) a0[i] = *(const bf16x8*)&lds[AOF(S, 0) + rowA + i * 512];
#pragma unroll
    for (int j = 0; j < 4; ++j) b0[j] = *(const bf16x8*)&lds[BOF(S, 0) + rowB + j * 512];
    if (st) {
        stage_half(Ab, m0, kb1, AOF(S ^ 1, 0));
        asm volatile("s_waitcnt vmcnt(2)" ::: "memory");   // confirms t.k1 regions
    } else {
        asm volatile("s_waitcnt vmcnt(0)" ::: "memory");   // tail: confirm all
    }
    __builtin_amdgcn_s_barrier();                          // publish block-wide
    asm volatile("s_waitcnt lgkmcnt(0)" ::: "memory");
    __builtin_amdgcn_sched_barrier(0);
    __builtin_amdgcn_s_setprio(1);
#pragma unroll
    for (int i = 0; i < 4; ++i)
#pragma unroll
        for (int j = 0; j < 4; ++j)
            acc[i][j] = MFMA16(a0[i], b0[j], acc[i][j]);
    __builtin_amdgcn_s_setprio(0);

    // ---- phase 2: reads k1 + stage B(t+1).k0 -> MFMA i0..3 @ k1 ----
#pragma unroll
    for (int i = 0; i < 4; ++i) a1[i] = *(const bf16x8*)&lds[AOF(S, 1) + rowA + i * 512];
#pragma unroll
    for (int j = 0; j < 4; ++j) b1[j] = *(const bf16x8*)&lds[BOF(S, 1) + rowB + j * 512];
    if (st) stage_half(Bb, n0, kb1, BOF(S ^ 1, 0));
    __builtin_amdgcn_s_barrier();
    asm volatile("s_waitcnt lgkmcnt(0)" ::: "memory");
    __builtin_amdgcn_sched_barrier(0);
    __builtin_amdgcn_s_setprio(1);
#pragma unroll
    for (int i = 0; i < 4; ++i)
#pragma unroll
        for (int j = 0; j < 4; ++j)
            acc[i][j] = MFMA16(a1[i], b1[j], acc[i][j]);
    __builtin_amdgcn_s_setprio(0);

    // ---- phase 3: reads k0 i4-7 + stage A(t+1).k1 -> MFMA i4..7 @ k0 ----
#pragma unroll
    for (int i = 0; i < 4; ++i) s0[i] = *(const bf16x8*)&lds[AOF(S, 0) + rowA + (4 + i) * 512];
    if (st) stage_half(Ab, m0, kb1 + 32, AOF(S ^ 1, 1));
    __builtin_amdgcn_s_barrier();
    asm volatile("s_waitcnt lgkmcnt(0)" ::: "memory");
    __builtin_amdgcn_sched_barrier(0);
    __builtin_amdgcn_s_setprio(1);
#pragma unroll
    for (int i = 0; i < 4; ++i)
#pragma unroll
        for (int j = 0; j < 4; ++j)
            acc[4 + i][j] = MFMA16(s0[i], b0[j], acc[4 + i][j]);
    __builtin_amdgcn_s_setprio(0);

    // ---- phase 4: reads k1 i4-7 + stage B(t+1).k1 + VMCNT(4) -> MFMA i4..7 @ k1 ----
#pragma unroll
    for (int i = 0; i < 4; ++i) s1[i] = *(const bf16x8*)&lds[AOF(S, 1) + rowA + (4 + i) * 512];
    if (st) {
        stage_half(Bb, n0, kb1 + 32, BOF(S ^ 1, 1));
        asm volatile("s_waitcnt vmcnt(4)" ::: "memory");   // confirms (t+1).k0 regions
    }
    __builtin_amdgcn_s_barrier();                          // publish block-wide
    asm volatile("s_waitcnt lgkmcnt(0)" ::: "memory");
    __builtin_amdgcn_sched_barrier(0);
    __builtin_amdgcn_s_setprio(1);
#pragma unroll
    for (int i = 0; i < 4; ++i)
#pragma unroll
        for (int j = 0; j < 4; ++j)
            acc[4 + i][j] = MFMA16(s1[i], b1[j], acc[4 + i][j]);
    __builtin_amdgcn_s_setprio(0);
}

__global__ void __launch_bounds__(512, 2)
kan_gemm8(const unsigned short* __restrict__ Ab,  // (2048, 20480) bf16 basis
          const unsigned short* __restrict__ Bb,  // (1024, 20480) bf16 W
          float* __restrict__ part) {             // (KS, 2048, 1024) partials
    __shared__ __align__(16) unsigned short lds[65536];   // 128 KiB

    constexpr int KPBk   = KR / KS;          // 2560
    constexpr int NTILES = KPBk / 64;        // 40

    const int id  = blockIdx.x;
    const int z   = id & 7;                  // K-split slice -> one per XCD
    const int ord = id >> 3;                 // 0..31
    const int mt  = ord & 7;
    const int nt  = ord >> 3;                // 0..3
    const int m0  = mt * 256;
    const int n0  = nt * 256;
    const int k0  = z * KPBk;

    const int tid  = threadIdx.x;
    const int wave = tid >> 6;               // 0..7
    const int lane = tid & 63;
    const int wm   = wave >> 2;              // 0..1 -> wave owns 128 M-rows
    const int wn   = wave & 3;               // 0..3 -> wave owns 64 N-cols

    const int srow32 = lane >> 2;                            // staging row 0..15
    const int scol32 = ((lane & 3) ^ ((lane >> 3) & 3)) * 8; // key=(R>>1)&3

    auto stage_half = [&](const unsigned short* __restrict__ src, int grow,
                          int kc, int lbase) {
        const unsigned short* g =
            src + (size_t)(grow + wave * 32 + srow32) * KR + kc + scol32;
        async_load16(g,                   &lds[lbase + wave * 1024]);
        async_load16(g + (size_t)16 * KR, &lds[lbase + wave * 1024 + 512]);
    };

    f32x4 acc[8][4];
#pragma unroll
    for (int i = 0; i < 8; ++i)
#pragma unroll
        for (int j = 0; j < 4; ++j) acc[i][j] = (f32x4){0.f, 0.f, 0.f, 0.f};

    const int q    = lane >> 4;
    const int r15  = lane & 15;
    const int cs   = (q ^ ((r15 >> 1) & 3)) * 8;   // read slot, key=(R>>1)&3
    const int rowA = (wm * 128 + r15) * 32 + cs;
    const int rowB = (wn * 64 + r15) * 32 + cs;

    // prologue: stage tile 0 in steady-state order; vmcnt(4) confirms k0
    // regions (k1 confirmed by ph1's vmcnt(2) before its barrier)
    stage_half(Ab, m0, k0,      AOF(0, 0));
    stage_half(Bb, n0, k0,      BOF(0, 0));
    stage_half(Ab, m0, k0 + 32, AOF(0, 1));
    stage_half(Bb, n0, k0 + 32, BOF(0, 1));
    asm volatile("s_waitcnt vmcnt(4)" ::: "memory");
    __builtin_amdgcn_s_barrier();

    for (int tt = 0; tt < NTILES; tt += 2) {
        tile_step<0>(tt,     NTILES, Ab, Bb, lds, acc, m0, n0, k0,
                     wave, rowA, rowB, srow32, scol32);
        tile_step<1>(tt + 1, NTILES, Ab, Bb, lds, acc, m0, n0, k0,
                     wave, rowA, rowB, srow32, scol32);
    }

    // epilogue: partials; C/D layout col=lane&15, row=(lane>>4)*4+reg
    float* dst = part + (size_t)z * OUT_ELEMS;
#pragma unroll
    for (int i = 0; i < 8; ++i)
#pragma unroll
        for (int j = 0; j < 4; ++j)
#pragma unroll
            for (int r = 0; r < 4; ++r) {
                const int row = m0 + wm * 128 + i * 16 + q * 4 + r;
                const int c   = n0 + wn * 64  + j * 16 + r15;
                dst[(size_t)row * OUT_DIM + c] = acc[i][j][r];
            }
}

// ---------------- reduce KS partial slices -> out ----------------------------
template <int KSr>
__global__ void kan_reduce(const float* __restrict__ part, float* __restrict__ out) {
    const int idx = (blockIdx.x * 256 + threadIdx.x) * 4;
    f32x4 s = *(const f32x4*)(part + idx);
#pragma unroll
    for (int z = 1; z < KSr; ++z)
        s += *(const f32x4*)(part + (size_t)z * OUT_ELEMS + idx);
    *(f32x4*)(out + idx) = s;
}

// ---------------- fallback (ws too small): correctness-only fp32 -------------
__global__ void kan_fallback(const float* __restrict__ x,
                             const float* __restrict__ W,
                             const float* __restrict__ knots,
                             float* __restrict__ out) {
    __shared__ float basis[256 * K_KNOTS];
    const int b = blockIdx.x;
    const int o = blockIdx.y * blockDim.x + threadIdx.x;
    const float invh = 1.0f / (knots[1] - knots[0]);
    const float* w = W + (size_t)o * KR;
    float sum = 0.f;
    for (int i0 = 0; i0 < IN_DIM; i0 += 256) {
        __syncthreads();
        for (int idx = threadIdx.x; idx < 256 * K_KNOTS; idx += blockDim.x) {
            const int i = i0 + idx / K_KNOTS;
            const int k = idx % K_KNOTS;
            const float d = (x[(size_t)b * IN_DIM + i] - knots[k]) * invh;
            basis[idx] = __expf(-0.5f * d * d);
        }
        __syncthreads();
        for (int r = 0; r < 256 * K_KNOTS; ++r)
            sum += basis[r] * w[(size_t)i0 * K_KNOTS + r];
    }
    out[(size_t)b * OUT_DIM + o] = sum;
}

extern "C" void kernel_launch(void* const* d_in, const int* in_sizes, int n_in,
                              void* d_out, int out_size, void* d_ws, size_t ws_size,
                              hipStream_t stream) {
    const float* x     = (const float*)d_in[0];
    const float* W     = (const float*)d_in[1];
    const float* knots = (const float*)d_in[2];
    float* out = (float*)d_out;

    const size_t basis_bytes = (size_t)B_DIM * KR * 2;              // 80 MiB
    const size_t wb_bytes    = (size_t)OUT_DIM * KR * 2;            // 40 MiB
    const size_t part_bytes  = (size_t)KS * OUT_ELEMS * 4;          // 64 MiB

    unsigned short* Ab = (unsigned short*)d_ws;
    unsigned short* Bb = (unsigned short*)((char*)d_ws + basis_bytes);
    float* part = (float*)((char*)d_ws + basis_bytes + wb_bytes);

    if (ws_size >= basis_bytes + wb_bytes + part_bytes) {
        // main path: vectorized prep + R11 race-free counted-vmcnt gemm + reduce.
        prep_kernel<<<dim3(NB_BASIS_BLK + NB_W_BLK), dim3(256), 0, stream>>>(
            x, (const float4*)W, knots, (uint4*)Ab, (uint4*)Bb);
        kan_gemm8<<<dim3(256), dim3(512), 0, stream>>>(Ab, Bb, part);
        kan_reduce<KS><<<dim3(OUT_ELEMS / (256 * 4)), dim3(256), 0, stream>>>(part, out);
    } else {
        kan_fallback<<<dim3(B_DIM, OUT_DIM / 256), dim3(256), 0, stream>>>(x, W, knots, out);
    }
}